// Round 6
// baseline (287.994 us; speedup 1.0000x reference)
//
#include <hip/hip_runtime.h>

// ---------------------------------------------------------------------------
// UpsampleLayer: out = Upsample2x_FIR( W @ x ) + bias   (upsample and 1x1 conv
// commute, so the GEMM runs at 64x64 instead of 127x127 -> 4x fewer FLOPs).
//
// Shapes: x[16][512][64][64] f32, w[512][512] f32, bias[512] f32 (zeros),
//         out[16][512][127][127] f32.
// Upsample (derived from lax.conv_general_dilated, lhs_dilation=2, pad=(2,1),
// kernel outer([1,3,3,1],[1,3,3,1])/16):
//   y[2m]   = (3*z[m] + z[m-1]) / 4      (z[-1] = 0)
//   y[2m+1] = (3*z[m] + z[m+1]) / 4
// per axis; output spatial size = 127.
// R1: one thread -> 2x2 quad (436 -> ~266 us; latency/sector-bound).
// R2: LDS-staged image (-15 us: LDS-pipe-bound, 8 ds_read_u16/row).
// R3: register row-march, no LDS (196 us; 3 sub-dword loads/row).
// R4: dwordx2-memcpy stores + 2 waves/img (178 us; sub-dword z loads remain
//     the bottleneck: ~3 GB of sector-granule L2 traffic).
// R5: one aligned u32 z-load/row (lane pairs share dwords) + one __shfl for
//     neighbors; inline-asm global_store_dwordx2 nt (dense stores, no L2/L3
//     pollution so z stays cache-resident).
// ---------------------------------------------------------------------------

#define B_   16
#define CIN  512
#define COUT 512
#define S_   4096   // 64*64
#define HO   127
#define WO   127

typedef unsigned int  u32;
typedef unsigned short u16;
typedef __attribute__((ext_vector_type(8))) short  bf16x8;
typedef __attribute__((ext_vector_type(8))) u16    u16x8;
typedef __attribute__((ext_vector_type(4))) float  f32x4;
typedef __attribute__((ext_vector_type(2))) float  f32x2;

static __device__ __forceinline__ u16 f2bf(float f) {
  u32 u = __float_as_uint(f);
  u += 0x7FFFu + ((u >> 16) & 1u);   // round-to-nearest-even (inputs finite)
  return (u16)(u >> 16);
}
static __device__ __forceinline__ float bf2f(u16 h) {
  return __uint_as_float(((u32)h) << 16);
}
// Forced 8B store with nt (non-temporal) flag. gfx950 HW supports
// dword-aligned dwordx2 (unaligned-access-mode); nt keeps the write-once
// out stream from evicting z/x in L2/L3.
static __device__ __forceinline__ void store2_nt(float* p, float a, float b) {
  f32x2 v; v.x = a; v.y = b;
  asm volatile("global_store_dwordx2 %0, %1, off nt" :: "v"(p), "v"(v));
}
static __device__ __forceinline__ void store1_nt(float* p, float a) {
  asm volatile("global_store_dword %0, %1, off nt" :: "v"(p), "v"(a));
}

#if defined(__has_builtin)
#if __has_builtin(__builtin_amdgcn_global_load_lds)
#define HAS_GLOAD 1
#endif
#endif
#ifndef HAS_GLOAD
#define HAS_GLOAD 0
#endif

#if HAS_GLOAD
static __device__ __forceinline__ void gload16(const char* g, char* l) {
  __builtin_amdgcn_global_load_lds(
      (const __attribute__((address_space(1))) unsigned int*)g,
      (__attribute__((address_space(3))) unsigned int*)l, 16, 0, 0);
}
#endif

// ---------------------------------------------------------------------------
// Tiled operand layout (both W and X^T), per 128(row) x 32(k) tile = 8 KiB:
//   tile = 512 units of 16B; unit u = kg*128 + r  (kg = (k%32)/8, r = row%128)
//   unit contents = 8 bf16, k = k0 + kg*8 + e.
// ---------------------------------------------------------------------------

// w[o][c] f32 -> wt tiled bf16. 32768 units total.
__global__ __launch_bounds__(256) void conv_w_kernel(
    const float* __restrict__ w, u16* __restrict__ wt) {
  int g = blockIdx.x * 256 + threadIdx.x;  // unit index
  int t_idx = g >> 9;                      // tile index (to*16 + tk)
  int u = g & 511;
  int to = t_idx >> 4, tk = t_idx & 15;
  int r = u & 127, kg = u >> 7;
  int o = to * 128 + r;
  int c = tk * 32 + kg * 8;
  const float4* src = reinterpret_cast<const float4*>(w + (size_t)o * CIN + c);
  float4 lo = src[0], hi = src[1];
  u16x8 pk;
  pk[0] = f2bf(lo.x); pk[1] = f2bf(lo.y); pk[2] = f2bf(lo.z); pk[3] = f2bf(lo.w);
  pk[4] = f2bf(hi.x); pk[5] = f2bf(hi.y); pk[6] = f2bf(hi.z); pk[7] = f2bf(hi.w);
  *reinterpret_cast<u16x8*>(wt + (size_t)g * 8) = pk;
}

// x[b][c][s] f32 -> xt tiled bf16 with (s,c) transpose.
// block = (ts, tk, b): 128 s-cols x 32 c-rows.
__global__ __launch_bounds__(256) void conv_x_kernel(
    const float* __restrict__ x, u16* __restrict__ xt) {
  int ts = blockIdx.x, tk = blockIdx.y, b = blockIdx.z;
  int t = threadIdx.x;
  __shared__ float lf[32 * 128];
  const float* src = x + ((size_t)(b * CIN + tk * 32)) * S_ + ts * 128;
#pragma unroll
  for (int i = 0; i < 4; ++i) {  // 1024 float4 total
    int q = i * 256 + t;
    int c = q >> 5, sq = q & 31;
    *reinterpret_cast<float4*>(&lf[c * 128 + sq * 4]) =
        *reinterpret_cast<const float4*>(src + (size_t)c * S_ + sq * 4);
  }
  __syncthreads();
  size_t tile_base = (((size_t)(b * 32 + ts)) * 16 + tk) * 512;  // in units
#pragma unroll
  for (int i = 0; i < 2; ++i) {
    int u = i * 256 + t;
    int kg = u >> 7, r = u & 127;
    u16x8 pk;
#pragma unroll
    for (int e = 0; e < 8; ++e) pk[e] = f2bf(lf[(kg * 8 + e) * 128 + r]);
    *reinterpret_cast<u16x8*>(xt + (tile_base + u) * 8) = pk;
  }
}

// GEMM: Z[b][o][s] = sum_c W[o][c] * X[b][c][s], 128x128 tile, BK=32,
// 4 waves (2x2), each wave 64x64 = 4x4 frags of mfma_f32_16x16x32_bf16.
__global__ __launch_bounds__(256) void gemm_kernel(
    const u16* __restrict__ wt, const u16* __restrict__ xt,
    u16* __restrict__ z) {
  int nt = blockIdx.x, mt = blockIdx.y, b = blockIdx.z;
  int t = threadIdx.x;
  __shared__ short lds[8192];  // A: bytes [0,8192), B: bytes [8192,16384)
  char* lA = (char*)&lds[0];
  char* lB = lA + 8192;

  int lane = t & 63, wid = t >> 6;
  int wr = wid >> 1, wc = wid & 1;
  int lr = lane & 15, kg = lane >> 4;

  f32x4 acc[4][4];
#pragma unroll
  for (int m = 0; m < 4; ++m)
#pragma unroll
    for (int n = 0; n < 4; ++n) acc[m][n] = f32x4{0.f, 0.f, 0.f, 0.f};

  const char* gA = (const char*)wt + (size_t)(mt * 16) * 8192;
  const char* gB = (const char*)xt + ((size_t)(b * 32 + nt)) * 16 * 8192;

  int abyte[4], bbyte[4];
#pragma unroll
  for (int m = 0; m < 4; ++m) abyte[m] = (kg * 128 + wr * 64 + m * 16 + lr) * 16;
#pragma unroll
  for (int n = 0; n < 4; ++n) bbyte[n] = (kg * 128 + wc * 64 + n * 16 + lr) * 16;

  for (int ks = 0; ks < 16; ++ks) {
    const char* pA = gA + (size_t)ks * 8192;
    const char* pB = gB + (size_t)ks * 8192;
#if HAS_GLOAD
    __syncthreads();  // previous compute done reading LDS
    gload16(pA + t * 16, lA + t * 16);
    gload16(pA + 4096 + t * 16, lA + 4096 + t * 16);
    gload16(pB + t * 16, lB + t * 16);
    gload16(pB + 4096 + t * 16, lB + 4096 + t * 16);
    __syncthreads();  // drains vmcnt, publishes LDS
#else
    u16x8 va0 = *reinterpret_cast<const u16x8*>(pA + t * 16);
    u16x8 va1 = *reinterpret_cast<const u16x8*>(pA + 4096 + t * 16);
    u16x8 vb0 = *reinterpret_cast<const u16x8*>(pB + t * 16);
    u16x8 vb1 = *reinterpret_cast<const u16x8*>(pB + 4096 + t * 16);
    __syncthreads();
    *reinterpret_cast<u16x8*>(lA + t * 16) = va0;
    *reinterpret_cast<u16x8*>(lA + 4096 + t * 16) = va1;
    *reinterpret_cast<u16x8*>(lB + t * 16) = vb0;
    *reinterpret_cast<u16x8*>(lB + 4096 + t * 16) = vb1;
    __syncthreads();
#endif
    bf16x8 av[4], bv[4];
#pragma unroll
    for (int m = 0; m < 4; ++m)
      av[m] = *reinterpret_cast<const bf16x8*>(lA + abyte[m]);
#pragma unroll
    for (int n = 0; n < 4; ++n)
      bv[n] = *reinterpret_cast<const bf16x8*>(lB + bbyte[n]);
#pragma unroll
    for (int m = 0; m < 4; ++m)
#pragma unroll
      for (int n = 0; n < 4; ++n)
        acc[m][n] = __builtin_amdgcn_mfma_f32_16x16x32_bf16(
            av[m], bv[n], acc[m][n], 0, 0, 0);
  }

  // C/D layout: col = lane&15 (s), row = (lane>>4)*4 + reg (o).
  int o_b = mt * 128 + wr * 64 + kg * 4;
  int s_b = nt * 128 + wc * 64 + lr;
#pragma unroll
  for (int m = 0; m < 4; ++m)
#pragma unroll
    for (int n = 0; n < 4; ++n) {
      f32x4 v = acc[m][n];
      size_t base = ((size_t)(b * COUT + o_b + m * 16)) * S_ + (s_b + n * 16);
#pragma unroll
      for (int r = 0; r < 4; ++r) z[base + (size_t)r * S_] = f2bf(v[r]);
    }
}

// R5 upsample: 2 waves per (b,o) image (rows [0,32)/[32,64), odd-half wave
// computes a halo h at m0-1). Lane n owns z col n -> out cols {2n, 2n+1}.
// Per row: ONE aligned u32 load (lane pairs 2k,2k+1 share dword k = z cols
// {2k,2k+1}; 32 unique dwords = dense 128B) + one __shfl for the neighbor
// dword. Neighbors:
//   even n: c=lo(own), l=hi(shfl n-2), r=hi(own)
//   odd  n: c=hi(own), l=lo(own),      r=lo(shfl n+1)
// Edge garbage (n=0 left, n=63 right) is tap-0-masked / feeds unused col 127.
//   h pair: hA = 1*z[m][n-1] + 3*z[m][n], hB = 3*z[m][n] + 1*z[m][n+1]
//   row 2m-1 = 3*h[m-1] + h[m];  row 2m = 1*h[m-1] + 3*h[m]
// Stores: forced global_store_dwordx2 nt (dense, no cache pollution).
__global__ __launch_bounds__(256) void upsample_kernel(
    const u16* __restrict__ z, const float* __restrict__ bias,
    float* __restrict__ out) {
  int t = threadIdx.x;
  int lane = t & 63;
  int gw = blockIdx.x * 4 + (t >> 6);  // global wave id
  int bo = gw >> 1;                    // b*512 + o
  int half = gw & 1;
  int m0 = half << 5;

  const u32* zimg32 = reinterpret_cast<const u32*>(z + ((size_t)bo << 12));
  float bv = bias[bo & 511];
  float* ob = out + (size_t)bo * (HO * WO) + 2 * lane;

  float wl = (lane == 0) ? 0.f : 1.f;  // left-tap mask
  bool has_j1 = (lane < 63);           // col 2n+1 <= 125 valid
  bool oddl = lane & 1;
  int shsrc = oddl ? (lane + 1) : (lane - 2);  // neighbor-dword source lane

  const u32* zp = zimg32 + (m0 << 5) + (lane >> 1);

  float hA_p = 0.f, hB_p = 0.f;
  if (half) {  // halo h at row m0-1
    u32 wv = zp[-32];
    u32 nb = (u32)__shfl((int)wv, shsrc, 64);
    u16 c16 = oddl ? (u16)(wv >> 16) : (u16)wv;
    u16 l16 = oddl ? (u16)wv : (u16)(nb >> 16);
    u16 r16 = oddl ? (u16)nb : (u16)(wv >> 16);
    float zc = bf2f(c16);
    hA_p = fmaf(3.f, zc, bf2f(l16) * wl);
    hB_p = fmaf(3.f, zc, bf2f(r16));
  }
  u32 wv = zp[0];

  for (int i = 0; i < 32; ++i) {
    int m = m0 + i;
    u32 nb = (u32)__shfl((int)wv, shsrc, 64);
    u16 c16 = oddl ? (u16)(wv >> 16) : (u16)wv;
    u16 l16 = oddl ? (u16)wv : (u16)(nb >> 16);
    u16 r16 = oddl ? (u16)nb : (u16)(wv >> 16);
    if (m < 63) { zp += 32; wv = zp[0]; }  // prefetch next row

    float zc = bf2f(c16), zl = bf2f(l16) * wl, zr = bf2f(r16);
    float hA = fmaf(3.f, zc, zl);
    float hB = fmaf(3.f, zc, zr);

    float* p_even = ob + (u32)(2 * m) * WO;
    if (m > 0) {  // row 2m-1 = 3*h_prev + h
      float* p_odd = p_even - WO;
      float v0 = fmaf(fmaf(3.f, hA_p, hA), 0.0625f, bv);
      float v1 = fmaf(fmaf(3.f, hB_p, hB), 0.0625f, bv);
      if (has_j1) store2_nt(p_odd, v0, v1); else store1_nt(p_odd, v0);
    }
    {  // row 2m = h_prev + 3*h
      float v0 = fmaf(fmaf(3.f, hA, hA_p), 0.0625f, bv);
      float v1 = fmaf(fmaf(3.f, hB, hB_p), 0.0625f, bv);
      if (has_j1) store2_nt(p_even, v0, v1); else store1_nt(p_even, v0);
    }
    hA_p = hA; hB_p = hB;
  }
}

// Slow but correct fallback if ws_size is insufficient (no workspace needed).
__global__ __launch_bounds__(256) void fallback_kernel(
    const float* __restrict__ x, const float* __restrict__ w,
    const float* __restrict__ bias, float* __restrict__ out) {
  u32 idx = blockIdx.x * 256u + threadIdx.x;
  const u32 total = (u32)B_ * COUT * HO * WO;
  if (idx >= total) return;
  u32 j = idx % WO;
  u32 r1 = idx / WO;
  u32 i = r1 % HO;
  u32 bo = r1 / HO;
  int o = (int)(bo & 511u);
  int b = (int)(bo >> 9);
  int m = (int)(i >> 1), n = (int)(j >> 1);
  int ie = !(i & 1), je = !(j & 1);
  int rA = ie ? m - 1 : m;
  int cA = je ? n - 1 : n;
  float w_r0 = ie ? 1.f : 3.f, w_r1 = ie ? 3.f : 1.f;
  float w_c0 = je ? 1.f : 3.f, w_c1 = je ? 3.f : 1.f;
  const float* xb = x + (size_t)b * CIN * S_;
  float acc = 0.f;
  for (int c = 0; c < CIN; ++c) {
    const float* xc = xb + (size_t)c * S_;
    float y = 0.f;
    if (rA >= 0) {
      if (cA >= 0) y += w_r0 * w_c0 * xc[rA * 64 + cA];
      y += w_r0 * w_c1 * xc[rA * 64 + cA + 1];
    }
    if (cA >= 0) y += w_r1 * w_c0 * xc[(rA + 1) * 64 + cA];
    y += w_r1 * w_c1 * xc[(rA + 1) * 64 + cA + 1];
    acc += y * w[(size_t)o * CIN + c];
  }
  out[idx] = acc * 0.0625f + bias[o];
}

extern "C" void kernel_launch(void* const* d_in, const int* in_sizes, int n_in,
                              void* d_out, int out_size, void* d_ws,
                              size_t ws_size, hipStream_t stream) {
  const float* x = (const float*)d_in[0];
  // d_in[1] = fir_kernel (deterministic, hard-coded taps above)
  const float* w = (const float*)d_in[2];
  const float* bias = (const float*)d_in[3];
  float* out = (float*)d_out;

  const size_t xt_bytes = (size_t)B_ * S_ * CIN * 2;       // 64 MiB
  const size_t wt_off = xt_bytes;
  const size_t wt_bytes = (size_t)COUT * CIN * 2;          // 512 KiB
  const size_t z_off = wt_off + ((wt_bytes + 255) & ~(size_t)255);
  const size_t need = z_off + (size_t)B_ * COUT * S_ * 2;  // ~128.5 MiB
  const size_t total_out = (size_t)B_ * COUT * HO * WO;
  const u32 nblk_out = (u32)((total_out + 255) / 256);

  if (ws_size >= need) {
    u16* xt = (u16*)d_ws;
    u16* wt = (u16*)((char*)d_ws + wt_off);
    u16* zz = (u16*)((char*)d_ws + z_off);
    conv_w_kernel<<<128, 256, 0, stream>>>(w, wt);
    conv_x_kernel<<<dim3(32, 16, B_), 256, 0, stream>>>(x, xt);
    gemm_kernel<<<dim3(32, 4, B_), 256, 0, stream>>>(wt, xt, zz);
    upsample_kernel<<<(B_ * COUT * 2) / 4, 256, 0, stream>>>(zz, bias, out);
  } else {
    fallback_kernel<<<nblk_out, 256, 0, stream>>>(x, w, bias, out);
  }
}

// Round 7
// 269.694 us; speedup vs baseline: 1.0679x; 1.0679x over previous
//
#include <hip/hip_runtime.h>

// ---------------------------------------------------------------------------
// UpsampleLayer: out = Upsample2x_FIR( W @ x ) + bias   (upsample and 1x1 conv
// commute, so the GEMM runs at 64x64 instead of 127x127 -> 4x fewer FLOPs).
//
// Shapes: x[16][512][64][64] f32, w[512][512] f32, bias[512] f32 (zeros),
//         out[16][512][127][127] f32.
// Upsample (derived from lax.conv_general_dilated, lhs_dilation=2, pad=(2,1)):
//   col j: g[j] = tA*z[n0] + tB*z[n0+1], n0=(j-1)>>1; even j: (tA,tB)=(1,3),
//   odd j: (3,1); j==0: tA=0.  Row r=2m: 3*g[m]+g[m-1]; r=2m-1: 3*g[m-1]+g[m].
// R1: thread->2x2 quad (436 -> ~266 us). R2: LDS image (LDS-pipe-bound).
// R3: register row-march (197 us). R4: +2 waves/img (178 us).
// R5: u32+shfl loads, asm nt dwordx2 stores -> REGRESSION (misaligned x2
//     stores split; shfl in dep chain). Reverted.
// R6: lane j owns cols {j, j+64} -> stores are two dense aligned dword spans
//     per row; FIR per col from 2 direct u16 loads. GEMM: BK=64 (8 iters,
//     half the barrier drains).
// ---------------------------------------------------------------------------

#define B_   16
#define CIN  512
#define COUT 512
#define S_   4096   // 64*64
#define HO   127
#define WO   127

typedef unsigned int  u32;
typedef unsigned short u16;
typedef __attribute__((ext_vector_type(8))) short  bf16x8;
typedef __attribute__((ext_vector_type(8))) u16    u16x8;
typedef __attribute__((ext_vector_type(4))) float  f32x4;

static __device__ __forceinline__ u16 f2bf(float f) {
  u32 u = __float_as_uint(f);
  u += 0x7FFFu + ((u >> 16) & 1u);   // round-to-nearest-even (inputs finite)
  return (u16)(u >> 16);
}
static __device__ __forceinline__ float bf2f(u16 h) {
  return __uint_as_float(((u32)h) << 16);
}

#if defined(__has_builtin)
#if __has_builtin(__builtin_amdgcn_global_load_lds)
#define HAS_GLOAD 1
#endif
#endif
#ifndef HAS_GLOAD
#define HAS_GLOAD 0
#endif

#if HAS_GLOAD
static __device__ __forceinline__ void gload16(const char* g, char* l) {
  __builtin_amdgcn_global_load_lds(
      (const __attribute__((address_space(1))) unsigned int*)g,
      (__attribute__((address_space(3))) unsigned int*)l, 16, 0, 0);
}
#endif

// ---------------------------------------------------------------------------
// Tiled operand layout (both W and X^T), per 128(row) x 32(k) tile = 8 KiB:
//   tile = 512 units of 16B; unit u = kg*128 + r  (kg = (k%32)/8, r = row%128)
//   unit contents = 8 bf16, k = k0 + kg*8 + e. k-tiles are contiguous.
// ---------------------------------------------------------------------------

// w[o][c] f32 -> wt tiled bf16. 32768 units total.
__global__ __launch_bounds__(256) void conv_w_kernel(
    const float* __restrict__ w, u16* __restrict__ wt) {
  int g = blockIdx.x * 256 + threadIdx.x;  // unit index
  int t_idx = g >> 9;                      // tile index (to*16 + tk)
  int u = g & 511;
  int to = t_idx >> 4, tk = t_idx & 15;
  int r = u & 127, kg = u >> 7;
  int o = to * 128 + r;
  int c = tk * 32 + kg * 8;
  const float4* src = reinterpret_cast<const float4*>(w + (size_t)o * CIN + c);
  float4 lo = src[0], hi = src[1];
  u16x8 pk;
  pk[0] = f2bf(lo.x); pk[1] = f2bf(lo.y); pk[2] = f2bf(lo.z); pk[3] = f2bf(lo.w);
  pk[4] = f2bf(hi.x); pk[5] = f2bf(hi.y); pk[6] = f2bf(hi.z); pk[7] = f2bf(hi.w);
  *reinterpret_cast<u16x8*>(wt + (size_t)g * 8) = pk;
}

// x[b][c][s] f32 -> xt tiled bf16 with (s,c) transpose.
// block = (ts, tk, b): 128 s-cols x 32 c-rows.
__global__ __launch_bounds__(256) void conv_x_kernel(
    const float* __restrict__ x, u16* __restrict__ xt) {
  int ts = blockIdx.x, tk = blockIdx.y, b = blockIdx.z;
  int t = threadIdx.x;
  __shared__ float lf[32 * 128];
  const float* src = x + ((size_t)(b * CIN + tk * 32)) * S_ + ts * 128;
#pragma unroll
  for (int i = 0; i < 4; ++i) {  // 1024 float4 total
    int q = i * 256 + t;
    int c = q >> 5, sq = q & 31;
    *reinterpret_cast<float4*>(&lf[c * 128 + sq * 4]) =
        *reinterpret_cast<const float4*>(src + (size_t)c * S_ + sq * 4);
  }
  __syncthreads();
  size_t tile_base = (((size_t)(b * 32 + ts)) * 16 + tk) * 512;  // in units
#pragma unroll
  for (int i = 0; i < 2; ++i) {
    int u = i * 256 + t;
    int kg = u >> 7, r = u & 127;
    u16x8 pk;
#pragma unroll
    for (int e = 0; e < 8; ++e) pk[e] = f2bf(lf[(kg * 8 + e) * 128 + r]);
    *reinterpret_cast<u16x8*>(xt + (tile_base + u) * 8) = pk;
  }
}

// GEMM: Z[b][o][s] = sum_c W[o][c] * X[b][c][s], 128x128 tile, BK=64 (two
// consecutive 8KB k-tiles per stage), 8 K-iters, 4 waves (2x2), each wave
// 64x64 = 4x4 frags of mfma_f32_16x16x32_bf16.
__global__ __launch_bounds__(256) void gemm_kernel(
    const u16* __restrict__ wt, const u16* __restrict__ xt,
    u16* __restrict__ z) {
  int nt = blockIdx.x, mt = blockIdx.y, b = blockIdx.z;
  int t = threadIdx.x;
  __shared__ __align__(16) char lds[32768];  // A: [0,16K), B: [16K,32K)
  char* lA = lds;
  char* lB = lds + 16384;

  int lane = t & 63, wid = t >> 6;
  int wr = wid >> 1, wc = wid & 1;
  int lr = lane & 15, kg = lane >> 4;

  f32x4 acc[4][4];
#pragma unroll
  for (int m = 0; m < 4; ++m)
#pragma unroll
    for (int n = 0; n < 4; ++n) acc[m][n] = f32x4{0.f, 0.f, 0.f, 0.f};

  const char* gA = (const char*)wt + (size_t)(mt * 16) * 8192;
  const char* gB = (const char*)xt + ((size_t)(b * 32 + nt)) * 16 * 8192;

  int abyte[4], bbyte[4];
#pragma unroll
  for (int m = 0; m < 4; ++m) abyte[m] = (kg * 128 + wr * 64 + m * 16 + lr) * 16;
#pragma unroll
  for (int n = 0; n < 4; ++n) bbyte[n] = (kg * 128 + wc * 64 + n * 16 + lr) * 16;

  for (int ks = 0; ks < 8; ++ks) {
    const char* pA = gA + (size_t)ks * 16384;
    const char* pB = gB + (size_t)ks * 16384;
#if HAS_GLOAD
    __syncthreads();  // previous compute done reading LDS
#pragma unroll
    for (int q = 0; q < 4; ++q) {
      gload16(pA + q * 4096 + t * 16, lA + q * 4096 + t * 16);
      gload16(pB + q * 4096 + t * 16, lB + q * 4096 + t * 16);
    }
    __syncthreads();  // drains vmcnt, publishes LDS
#else
    u16x8 va[4], vb[4];
#pragma unroll
    for (int q = 0; q < 4; ++q) {
      va[q] = *reinterpret_cast<const u16x8*>(pA + q * 4096 + t * 16);
      vb[q] = *reinterpret_cast<const u16x8*>(pB + q * 4096 + t * 16);
    }
    __syncthreads();
#pragma unroll
    for (int q = 0; q < 4; ++q) {
      *reinterpret_cast<u16x8*>(lA + q * 4096 + t * 16) = va[q];
      *reinterpret_cast<u16x8*>(lB + q * 4096 + t * 16) = vb[q];
    }
    __syncthreads();
#endif
#pragma unroll
    for (int kg2 = 0; kg2 < 2; ++kg2) {
      bf16x8 av[4], bv[4];
#pragma unroll
      for (int m = 0; m < 4; ++m)
        av[m] = *reinterpret_cast<const bf16x8*>(lA + kg2 * 8192 + abyte[m]);
#pragma unroll
      for (int n = 0; n < 4; ++n)
        bv[n] = *reinterpret_cast<const bf16x8*>(lB + kg2 * 8192 + bbyte[n]);
#pragma unroll
      for (int m = 0; m < 4; ++m)
#pragma unroll
        for (int n = 0; n < 4; ++n)
          acc[m][n] = __builtin_amdgcn_mfma_f32_16x16x32_bf16(
              av[m], bv[n], acc[m][n], 0, 0, 0);
    }
  }

  // C/D layout: col = lane&15 (s), row = (lane>>4)*4 + reg (o).
  int o_b = mt * 128 + wr * 64 + kg * 4;
  int s_b = nt * 128 + wc * 64 + lr;
#pragma unroll
  for (int m = 0; m < 4; ++m)
#pragma unroll
    for (int n = 0; n < 4; ++n) {
      f32x4 v = acc[m][n];
      size_t base = ((size_t)(b * COUT + o_b + m * 16)) * S_ + (s_b + n * 16);
#pragma unroll
      for (int r = 0; r < 4; ++r) z[base + (size_t)r * S_] = f2bf(v[r]);
    }
}

// R6 upsample: 2 waves per (b,o) image (rows [0,32)/[32,64); odd-half wave
// computes halo g at m0-1). Lane j owns OUTPUT cols {j, j+64} -> every row's
// stores are two dense, dword-aligned wave spans (256B + 252B). FIR for col
// j from z[n0], z[n0+1] (n0=(j-1)>>1, 2 u16 loads); col j+64 uses n0+32.
__global__ __launch_bounds__(256) void upsample_kernel(
    const u16* __restrict__ z, const float* __restrict__ bias,
    float* __restrict__ out) {
  int t = threadIdx.x;
  int lane = t & 63;
  int gw = blockIdx.x * 4 + (t >> 6);  // global wave id
  int bo = gw >> 1;                    // b*512 + o
  int half = gw & 1;
  int m0 = half << 5;

  const u16* zimg = z + ((size_t)bo << 12);
  float bv = bias[bo & 511];
  float* ob = out + (size_t)bo * (HO * WO);

  int j = lane;
  int n0 = (j - 1) >> 1;               // arithmetic; -1 at j==0
  float tA = (j & 1) ? 3.f : 1.f;
  float tB = (j & 1) ? 1.f : 3.f;
  float tA0 = (j == 0) ? 0.f : tA;     // left tap masked at col 0
  int i00 = (n0 < 0) ? 0 : n0;         // col j taps: z[i00], z[i01]
  int i01 = n0 + 1;
  int i10 = n0 + 32;                   // col j+64 taps: z[i10], z[i11]
  int i11 = (j == 63) ? 63 : n0 + 33;  // clamp: lane63 col1 unused, avoid OOB
  bool hasc1 = (j < 63);               // col j+64 <= 126 valid

  const u16* zr = zimg + (m0 << 6);
  float g0_p = 0.f, g1_p = 0.f;
  if (half) {  // halo g at row m0-1
    const u16* q = zr - 64;
    g0_p = fmaf(tA0, bf2f(q[i00]), tB * bf2f(q[i01]));
    g1_p = fmaf(tA, bf2f(q[i10]), tB * bf2f(q[i11]));
  }
  u16 a0_ = zr[i00], a1_ = zr[i01], b0_ = zr[i10], b1_ = zr[i11];

  for (int i = 0; i < 32; ++i) {
    int m = m0 + i;
    float zA0 = bf2f(a0_), zB0 = bf2f(a1_);
    float zA1 = bf2f(b0_), zB1 = bf2f(b1_);
    if (m < 63) {  // prefetch next row
      zr += 64;
      a0_ = zr[i00]; a1_ = zr[i01]; b0_ = zr[i10]; b1_ = zr[i11];
    }
    float g0 = fmaf(tA0, zA0, tB * zB0);
    float g1 = fmaf(tA, zA1, tB * zB1);

    float* p_even = ob + (u32)(2 * m) * WO;
    if (m > 0) {  // row 2m-1 = 3*g_prev + g
      float* p_odd = p_even - WO;
      p_odd[j] = fmaf(fmaf(3.f, g0_p, g0), 0.0625f, bv);
      if (hasc1) p_odd[64 + j] = fmaf(fmaf(3.f, g1_p, g1), 0.0625f, bv);
    }
    // row 2m = g_prev + 3*g
    p_even[j] = fmaf(fmaf(3.f, g0, g0_p), 0.0625f, bv);
    if (hasc1) p_even[64 + j] = fmaf(fmaf(3.f, g1, g1_p), 0.0625f, bv);
    g0_p = g0; g1_p = g1;
  }
}

// Slow but correct fallback if ws_size is insufficient (no workspace needed).
__global__ __launch_bounds__(256) void fallback_kernel(
    const float* __restrict__ x, const float* __restrict__ w,
    const float* __restrict__ bias, float* __restrict__ out) {
  u32 idx = blockIdx.x * 256u + threadIdx.x;
  const u32 total = (u32)B_ * COUT * HO * WO;
  if (idx >= total) return;
  u32 j = idx % WO;
  u32 r1 = idx / WO;
  u32 i = r1 % HO;
  u32 bo = r1 / HO;
  int o = (int)(bo & 511u);
  int b = (int)(bo >> 9);
  int m = (int)(i >> 1), n = (int)(j >> 1);
  int ie = !(i & 1), je = !(j & 1);
  int rA = ie ? m - 1 : m;
  int cA = je ? n - 1 : n;
  float w_r0 = ie ? 1.f : 3.f, w_r1 = ie ? 3.f : 1.f;
  float w_c0 = je ? 1.f : 3.f, w_c1 = je ? 3.f : 1.f;
  const float* xb = x + (size_t)b * CIN * S_;
  float acc = 0.f;
  for (int c = 0; c < CIN; ++c) {
    const float* xc = xb + (size_t)c * S_;
    float y = 0.f;
    if (rA >= 0) {
      if (cA >= 0) y += w_r0 * w_c0 * xc[rA * 64 + cA];
      y += w_r0 * w_c1 * xc[rA * 64 + cA + 1];
    }
    if (cA >= 0) y += w_r1 * w_c0 * xc[(rA + 1) * 64 + cA];
    y += w_r1 * w_c1 * xc[(rA + 1) * 64 + cA + 1];
    acc += y * w[(size_t)o * CIN + c];
  }
  out[idx] = acc * 0.0625f + bias[o];
}

extern "C" void kernel_launch(void* const* d_in, const int* in_sizes, int n_in,
                              void* d_out, int out_size, void* d_ws,
                              size_t ws_size, hipStream_t stream) {
  const float* x = (const float*)d_in[0];
  // d_in[1] = fir_kernel (deterministic, hard-coded taps above)
  const float* w = (const float*)d_in[2];
  const float* bias = (const float*)d_in[3];
  float* out = (float*)d_out;

  const size_t xt_bytes = (size_t)B_ * S_ * CIN * 2;       // 64 MiB
  const size_t wt_off = xt_bytes;
  const size_t wt_bytes = (size_t)COUT * CIN * 2;          // 512 KiB
  const size_t z_off = wt_off + ((wt_bytes + 255) & ~(size_t)255);
  const size_t need = z_off + (size_t)B_ * COUT * S_ * 2;  // ~128.5 MiB
  const size_t total_out = (size_t)B_ * COUT * HO * WO;
  const u32 nblk_out = (u32)((total_out + 255) / 256);

  if (ws_size >= need) {
    u16* xt = (u16*)d_ws;
    u16* wt = (u16*)((char*)d_ws + wt_off);
    u16* zz = (u16*)((char*)d_ws + z_off);
    conv_w_kernel<<<128, 256, 0, stream>>>(w, wt);
    conv_x_kernel<<<dim3(32, 16, B_), 256, 0, stream>>>(x, xt);
    gemm_kernel<<<dim3(32, 4, B_), 256, 0, stream>>>(wt, xt, zz);
    upsample_kernel<<<(B_ * COUT * 2) / 4, 256, 0, stream>>>(zz, bias, out);
  } else {
    fallback_kernel<<<nblk_out, 256, 0, stream>>>(x, w, bias, out);
  }
}